// Round 10
// baseline (321.385 us; speedup 1.0000x reference)
//
#include <hip/hip_runtime.h>
#include <math.h>

// ---------------------------------------------------------------------------
// Problem constants (fixed production sizes from the reference)
// ---------------------------------------------------------------------------
namespace {
constexpr int cB  = 64;
constexpr int cNQ = 32;
constexpr int cND = 512;
constexpr int cNd = cB * cND;   // 32768
constexpr int cNq = cB * cNQ;   // 2048
constexpr int cEd = cNd * 8;    // 262144 (exactly 4096 per graph)
constexpr int cEq = cNq * 8;    // 16384  (exactly 256 per graph)
constexpr int LD_STRIDE = 516;
constexpr int NB_CVT = 2188, NB_T2BF = 808, NB_CNT = (cEd + cEq) / 256;
constexpr int NB_FILL = (cEd + cEq) / 256;  // 1088
}

#define F4C(p) (*(const float4*)(p))

typedef __attribute__((ext_vector_type(8))) __bf16 bf16x8;
typedef __attribute__((ext_vector_type(4))) float floatx4;

__device__ __forceinline__ ushort f2bf(float f) {
  union { float f; unsigned u; } v;
  v.f = f;
  unsigned u = v.u;
  return (ushort)((u + 0x7fffu + ((u >> 16) & 1u)) >> 16);
}
__device__ __forceinline__ float bf2f(ushort u) {
  union { unsigned u; float f; } v;
  v.u = ((unsigned)u) << 16;
  return v.f;
}
__device__ __forceinline__ float4 us4f4(ushort4 u) {
  return make_float4(bf2f(u.x), bf2f(u.y), bf2f(u.z), bf2f(u.w));
}
__device__ __forceinline__ ushort4 f4us4(float4 f) {
  ushort4 o;
  o.x = f2bf(f.x); o.y = f2bf(f.y); o.z = f2bf(f.z); o.w = f2bf(f.w);
  return o;
}
__device__ __forceinline__ float fexp2(float x) {
#if __has_builtin(__builtin_amdgcn_exp2f)
  return __builtin_amdgcn_exp2f(x);
#else
  return exp2f(x);
#endif
}
__device__ __forceinline__ float frcp(float x) {
#if __has_builtin(__builtin_amdgcn_rcpf)
  return __builtin_amdgcn_rcpf(x);
#else
  return 1.0f / x;
#endif
}
__device__ __forceinline__ float fsigmoid(float z) {
  return frcp(1.0f + fexp2(z * -1.4426950408889634f));
}
__device__ __forceinline__ float fexp(float x) { return fexp2(x * 1.4426950408889634f); }

// XCD-affinity swizzle (blockIdx%8 -> XCD round-robin heuristic); low 6 bits
__device__ __forceinline__ int swz_g(int j) { return (((j >> 3) & 7) << 3) | (j & 7); }

// ---------------------------------------------------------------------------
// Device helpers
// ---------------------------------------------------------------------------
__device__ __forceinline__ void dev_gather_node(
    int node, int l, const ushort* __restrict__ hs, const int* __restrict__ rp,
    const int* __restrict__ cnt, const int* __restrict__ col,
    const float* __restrict__ dinv, const float* __restrict__ bias,
    ushort* __restrict__ outp) {
  int c = cnt[node], s0 = rp[node];
  float dt = dinv[node];
  float4 acc = us4f4(*(const ushort4*)(hs + (size_t)node * 128 + l * 4));
  int cm = c < 32 ? c : 32;
  for (int j0 = 0; j0 < cm; j0 += 8) {
    int ss[8];
    ushort4 v[8];
#pragma unroll
    for (int t = 0; t < 8; ++t) {
      int jj = j0 + t;
      ss[t] = (jj < cm) ? col[s0 + jj] : -1;
    }
#pragma unroll
    for (int t = 0; t < 8; ++t)
      if (ss[t] >= 0) v[t] = *(const ushort4*)(hs + (size_t)ss[t] * 128 + l * 4);
#pragma unroll
    for (int t = 0; t < 8; ++t) {
      if (ss[t] >= 0) {
        float4 f = us4f4(v[t]);
        acc.x += f.x; acc.y += f.y; acc.z += f.z; acc.w += f.w;
      }
    }
  }
  for (int j = 32; j < c; ++j) {
    int s = col[s0 + j];
    float4 f = us4f4(*(const ushort4*)(hs + (size_t)s * 128 + l * 4));
    acc.x += f.x; acc.y += f.y; acc.z += f.z; acc.w += f.w;
  }
  float4 bv = F4C(bias + l * 4);
  float4 r;
  r.x = fmaxf(acc.x * dt + bv.x, 0.0f);
  r.y = fmaxf(acc.y * dt + bv.y, 0.0f);
  r.z = fmaxf(acc.z * dt + bv.z, 0.0f);
  r.w = fmaxf(acc.w * dt + bv.w, 0.0f);
  *(ushort4*)(outp + (size_t)node * 128 + l * 4) = f4us4(r);
}

// 128-rows-per-block GEMM (KD=128), 8 waves x 16 rows, bf16 MFMA
__device__ __forceinline__ void dev_gemm128(
    int mloc, const ushort* __restrict__ X, const ushort* __restrict__ WT,
    const float* __restrict__ dv, ushort* __restrict__ H, size_t hbase,
    int col, int quad) {
  floatx4 acc[8];
#pragma unroll
  for (int ct = 0; ct < 8; ++ct)
#pragma unroll
    for (int r = 0; r < 4; ++r) acc[ct][r] = 0.0f;
#pragma unroll
  for (int kc = 0; kc < 4; ++kc) {
    bf16x8 a = *(const bf16x8*)(X + (size_t)(mloc + col) * 128 + kc * 32 + quad * 8);
#pragma unroll
    for (int ct = 0; ct < 8; ++ct) {
      bf16x8 b = *(const bf16x8*)(WT + (size_t)(ct * 16 + col) * 128 + kc * 32 + quad * 8);
      acc[ct] = __builtin_amdgcn_mfma_f32_16x16x32_bf16(a, b, acc[ct], 0, 0, 0);
    }
  }
  float sc[4];
#pragma unroll
  for (int r = 0; r < 4; ++r) sc[r] = dv[mloc + quad * 4 + r];
#pragma unroll
  for (int ct = 0; ct < 8; ++ct)
#pragma unroll
    for (int r = 0; r < 4; ++r)
      H[(hbase + mloc + quad * 4 + r) * 128 + ct * 16 + col] = f2bf(acc[ct][r] * sc[r]);
}

// ---------------------------------------------------------------------------
// D1 front: conversions + weight transposes + edge counts. grid 4084 x 256.
// ---------------------------------------------------------------------------
__global__ __launch_bounds__(256) void k_front(
    const float* __restrict__ xd, const float* __restrict__ xq,
    const float* __restrict__ v0, const float* __restrict__ v1,
    const float* __restrict__ v2, ushort* __restrict__ oxd, ushort* __restrict__ oxq,
    ushort* __restrict__ ov0, ushort* __restrict__ ov1, ushort* __restrict__ ov2,
    const float* __restrict__ W1, const float* __restrict__ W2,
    const float* __restrict__ W3, const float* __restrict__ Wn0,
    const float* __restrict__ Wn1, const float* __restrict__ Wn2,
    ushort* __restrict__ o1, ushort* __restrict__ o2, ushort* __restrict__ o3,
    ushort* __restrict__ on0, ushort* __restrict__ on1, ushort* __restrict__ on2,
    const int* __restrict__ dst_d, const int* __restrict__ dst_q,
    int* __restrict__ cnt_d, int* __restrict__ cnt_q) {
  __shared__ float tile[32][33];
  int blk = blockIdx.x, tid = threadIdx.x;
  if (blk < NB_CVT) {
    const float* src;
    ushort* dst;
    int i;
    if (blk < 2048) { src = xd; dst = oxd; i = blk * 256 + tid; }
    else if (blk < 2176) { src = xq; dst = oxq; i = (blk - 2048) * 256 + tid; }
    else if (blk < 2180) { src = v0; dst = ov0; i = (blk - 2176) * 256 + tid; }
    else if (blk < 2184) { src = v1; dst = ov1; i = (blk - 2180) * 256 + tid; }
    else { src = v2; dst = ov2; i = (blk - 2184) * 256 + tid; }
    *(ushort4*)(dst + (size_t)i * 4) = f4us4(F4C(src + (size_t)i * 4));
  } else if (blk < NB_CVT + NB_T2BF) {
    int b5 = blk - NB_CVT;
    const float* in;
    ushort* out;
    int R, C, bt, t;
    if (b5 < 8)        { in = W1;  out = o1;  R = 64;  C = 128; bt = 0; t = b5; }
    else if (b5 < 24)  { in = W2;  out = o2;  R = 128; C = 128; bt = 0; t = b5 - 8; }
    else if (b5 < 40)  { in = W3;  out = o3;  R = 128; C = 128; bt = 0; t = b5 - 24; }
    else if (b5 < 296) { in = Wn0; out = on0; R = 128; C = 128; bt = (b5 - 40) >> 4;  t = (b5 - 40) & 15; }
    else if (b5 < 552) { in = Wn1; out = on1; R = 128; C = 128; bt = (b5 - 296) >> 4; t = (b5 - 296) & 15; }
    else               { in = Wn2; out = on2; R = 128; C = 128; bt = (b5 - 552) >> 4; t = (b5 - 552) & 15; }
    int tilesC = C >> 5;
    int tr = t / tilesC, tc = t - tr * tilesC;
    int tx = tid & 31, ty = tid >> 5;
    const float* ib = in + (size_t)bt * R * C;
    ushort* ob = out + (size_t)bt * R * C;
#pragma unroll
    for (int i = 0; i < 4; ++i)
      tile[ty + i * 8][tx] = ib[(tr * 32 + ty + i * 8) * C + tc * 32 + tx];
    __syncthreads();
#pragma unroll
    for (int i = 0; i < 4; ++i)
      ob[(size_t)(tc * 32 + ty + i * 8) * R + tr * 32 + tx] = f2bf(tile[tx][ty + i * 8]);
  } else {
    int i = (blk - NB_CVT - NB_T2BF) * 256 + tid;
    if (i < cEd) atomicAdd(&cnt_d[dst_d[i]], 1);
    else atomicAdd(&cnt_q[dst_q[i - cEd]], 1);
  }
}

// ---------------------------------------------------------------------------
// D2: per-graph local scans + dinv. grid 136 x 512.
// ---------------------------------------------------------------------------
__global__ __launch_bounds__(512) void k_scan_dinv(
    const int* __restrict__ cnt_d, const int* __restrict__ cnt_q,
    int* __restrict__ rp_d, int* __restrict__ rp_q,
    float* __restrict__ dinv_d, float* __restrict__ dinv_q) {
  __shared__ int sh[512];
  int blk = blockIdx.x, tid = threadIdx.x;
  if (blk < 64) {
    int v = cnt_d[blk * 512 + tid];
    sh[tid] = v;
    __syncthreads();
    for (int off = 1; off < 512; off <<= 1) {
      int t = (tid >= off) ? sh[tid - off] : 0;
      __syncthreads();
      sh[tid] += t;
      __syncthreads();
    }
    rp_d[blk * 512 + tid] = blk * 4096 + sh[tid] - v;
  } else if (blk < 68) {
    int g = (blk - 64) * 16 + (tid >> 5);
    int lane32 = tid & 31;
    int v = cnt_q[g * 32 + lane32];
    int incl = v;
#pragma unroll
    for (int off = 1; off < 32; off <<= 1) {
      int t = __shfl_up(incl, off, 32);
      if (lane32 >= off) incl += t;
    }
    rp_q[g * 32 + lane32] = g * 256 + incl - v;
  } else {
    int i = (blk - 68) * 512 + tid;
    if (i < cNd) dinv_d[i] = 1.0f / sqrtf((float)(cnt_d[i] + 1));
    else dinv_q[i - cNd] = 1.0f / sqrtf((float)(cnt_q[i - cNd] + 1));
  }
}

// ---------------------------------------------------------------------------
// D3: CSR fill + full GCN GEMM layer 1 (KD=64). grid 1632 x 256.
// ---------------------------------------------------------------------------
__global__ __launch_bounds__(256) void k_fill_gemm1(
    const int* __restrict__ src_d, const int* __restrict__ dst_d,
    const int* __restrict__ src_q, const int* __restrict__ dst_q,
    const int* __restrict__ rp_d, const int* __restrict__ rp_q,
    int* __restrict__ cur_d, int* __restrict__ cur_q, int* __restrict__ col_d,
    int* __restrict__ col_q, const ushort* __restrict__ xdbf,
    const ushort* __restrict__ xqbf, const ushort* __restrict__ w1T,
    const float* __restrict__ dinv_d, const float* __restrict__ dinv_q,
    ushort* __restrict__ htmp) {
  int blk = blockIdx.x, tid = threadIdx.x;
  if (blk < NB_FILL) {
    int i = blk * 256 + tid;
    if (i < cEd) {
      int d = dst_d[i];
      int p = atomicAdd(&cur_d[d], 1);
      col_d[rp_d[d] + p] = src_d[i];
    } else {
      int j = i - cEd;
      int d = dst_q[j];
      int p = atomicAdd(&cur_q[d], 1);
      col_q[rp_q[d] + p] = src_q[j];
    }
    return;
  }
  int blk2 = blk - NB_FILL;  // [0,544): data [0,512) swizzled, query [512,544)
  int wave = tid >> 6, lane = tid & 63;
  int col = lane & 15, quad = lane >> 4;
  bool isQ = blk2 >= 512;
  int node0;
  if (isQ) node0 = (blk2 - 512) * 64;
  else node0 = swz_g(blk2) * 512 + (blk2 >> 6) * 64;
  int mloc = node0 + wave * 16;
  const ushort* X = isQ ? xqbf : xdbf;
  const float* dv = isQ ? dinv_q : dinv_d;
  size_t hbase = isQ ? (size_t)cNd : 0;
  floatx4 acc[8];
#pragma unroll
  for (int ct = 0; ct < 8; ++ct)
#pragma unroll
    for (int r = 0; r < 4; ++r) acc[ct][r] = 0.0f;
#pragma unroll
  for (int kc = 0; kc < 2; ++kc) {
    bf16x8 a = *(const bf16x8*)(X + (size_t)(mloc + col) * 64 + kc * 32 + quad * 8);
#pragma unroll
    for (int ct = 0; ct < 8; ++ct) {
      bf16x8 b = *(const bf16x8*)(w1T + (size_t)(ct * 16 + col) * 64 + kc * 32 + quad * 8);
      acc[ct] = __builtin_amdgcn_mfma_f32_16x16x32_bf16(a, b, acc[ct], 0, 0, 0);
    }
  }
  float sc[4];
#pragma unroll
  for (int r = 0; r < 4; ++r) sc[r] = dv[mloc + quad * 4 + r];
#pragma unroll
  for (int ct = 0; ct < 8; ++ct)
#pragma unroll
    for (int r = 0; r < 4; ++r)
      htmp[(hbase + mloc + quad * 4 + r) * 128 + ct * 16 + col] = f2bf(acc[ct][r] * sc[r]);
}

// ---------------------------------------------------------------------------
// E1 mega-kernel. 512 threads. Sections by aux:
//  aux 0: [0,2048) gather_d | [2048,2176) gather_q                (grid 2176)
//  aux 1: [0,2048) gather_d | [2048,2560) qw | [2560,2576) gemm_q (grid 2576/2560)
//  aux 2: [0,512) qw | [512,528) gemm_q                           (grid 528)
// ---------------------------------------------------------------------------
__global__ __launch_bounds__(512, 4) void k_e1(
    int aux, ushort* __restrict__ htmp, const int* __restrict__ rp_d,
    const int* __restrict__ cnt_d, const int* __restrict__ col_d,
    const float* __restrict__ dinv_d, const int* __restrict__ rp_q,
    const int* __restrict__ cnt_q, const int* __restrict__ col_q,
    const float* __restrict__ dinv_q, const float* __restrict__ bias,
    ushort* __restrict__ dbf, ushort* __restrict__ qbf_out,
    const ushort* __restrict__ qbf_lvl, const ushort* __restrict__ wnT,
    ushort* __restrict__ qw, const ushort* __restrict__ gWT) {
  int blk = blockIdx.x, tid = threadIdx.x;
  int wave = tid >> 6, lane = tid & 63;
  int col = lane & 15, quad = lane >> 4;
  int sec, sblk;
  if (aux == 0) {
    if (blk < 2048) { sec = 0; sblk = blk; } else { sec = 1; sblk = blk - 2048; }
  } else if (aux == 1) {
    if (blk < 2048) { sec = 0; sblk = blk; }
    else if (blk < 2560) { sec = 2; sblk = blk - 2048; }
    else { sec = 3; sblk = blk - 2560; }
  } else {
    if (blk < 512) { sec = 2; sblk = blk; } else { sec = 3; sblk = blk - 512; }
  }

  if (sec == 0) {  // gather_d: 2048 blocks x 16 nodes
    int node = swz_g(sblk & 63) * 512 + (sblk >> 6) * 16 + (tid >> 5);
    dev_gather_node(node, tid & 31, htmp, rp_d, cnt_d, col_d, dinv_d, bias, dbf);
  } else if (sec == 1) {  // gather_q: 128 blocks x 16 nodes
    int node = swz_g(sblk & 63) * 32 + (sblk >> 6) * 16 + (tid >> 5);
    dev_gather_node(node, tid & 31, htmp + (size_t)cNd * 128, rp_q, cnt_q, col_q,
                    dinv_q, bias, qbf_out);
  } else if (sec == 2) {  // qw: 512 blocks, block = (b, k-pair), wave>>2 picks k
    int b = swz_g(sblk & 63);
    int k = (sblk >> 6) * 2 + (wave >> 2);
    int et0 = (wave & 3) * 2;
    floatx4 acc[2][2];
#pragma unroll
    for (int qt = 0; qt < 2; ++qt)
#pragma unroll
      for (int ei = 0; ei < 2; ++ei)
#pragma unroll
        for (int r = 0; r < 4; ++r) acc[qt][ei][r] = 0.0f;
#pragma unroll
    for (int kc = 0; kc < 4; ++kc) {
      bf16x8 a0 = *(const bf16x8*)(qbf_lvl + (size_t)(b * 32 + col) * 128 + kc * 32 + quad * 8);
      bf16x8 a1 = *(const bf16x8*)(qbf_lvl + (size_t)(b * 32 + 16 + col) * 128 + kc * 32 + quad * 8);
#pragma unroll
      for (int ei = 0; ei < 2; ++ei) {
        bf16x8 bf = *(const bf16x8*)(wnT + (size_t)(k * 128 + (et0 + ei) * 16 + col) * 128 +
                                     kc * 32 + quad * 8);
        acc[0][ei] = __builtin_amdgcn_mfma_f32_16x16x32_bf16(a0, bf, acc[0][ei], 0, 0, 0);
        acc[1][ei] = __builtin_amdgcn_mfma_f32_16x16x32_bf16(a1, bf, acc[1][ei], 0, 0, 0);
      }
    }
#pragma unroll
    for (int qt = 0; qt < 2; ++qt)
#pragma unroll
      for (int ei = 0; ei < 2; ++ei)
#pragma unroll
        for (int r = 0; r < 4; ++r)
          qw[((size_t)(b * 16 + k) << 12) + (qt * 16 + quad * 4 + r) * 128 +
             (et0 + ei) * 16 + col] = f2bf(acc[qt][ei][r]);
  } else {  // gemm_q (next layer, KD=128): 16 blocks x 128 rows
    int mloc = sblk * 128 + wave * 16;
    dev_gemm128(mloc, qbf_lvl, gWT, dinv_q, htmp, (size_t)cNd, col, quad);
  }
}

// ---------------------------------------------------------------------------
// E2 mega-kernel: [0,128) fused level | [128,384) gemm_d next | [384,512)
// gather_q next. 512 threads. (l=2: grid 128.)
// ---------------------------------------------------------------------------
__global__ __launch_bounds__(512, 2) void k_e2(
    const ushort* __restrict__ qbf, const ushort* __restrict__ dbf,
    const ushort* __restrict__ qw, const ushort* __restrict__ vnbf,
    const float* __restrict__ bn, const float* __restrict__ cw,
    const float* __restrict__ w_end, const float* __restrict__ b_end,
    int o1, int o2, int hasF, int do_sm, int mode, int widx,
    float* __restrict__ accb, float* __restrict__ out,
    const ushort* __restrict__ gWT, const float* __restrict__ dinv_d,
    const float* __restrict__ dinv_q, ushort* __restrict__ htmp,
    const int* __restrict__ rp_q, const int* __restrict__ cnt_q,
    const int* __restrict__ col_q, const float* __restrict__ bias_next,
    ushort* __restrict__ qbf_next) {
  __shared__ float s_ld[16 * LD_STRIDE];
  __shared__ float s_lq[16 * 16];
  __shared__ float s_red[16 * 8];
  int tid = threadIdx.x;
  int wave = tid >> 6, lane = tid & 63;
  int col = lane & 15, quad = lane >> 4;

  if (blockIdx.x >= 384) {  // gather_q for next layer
    int j = blockIdx.x - 384;
    int node = swz_g(j & 63) * 32 + (j >> 6) * 16 + (tid >> 5);
    dev_gather_node(node, tid & 31, htmp + (size_t)cNd * 128, rp_q, cnt_q, col_q,
                    dinv_q, bias_next, qbf_next);
    return;
  }
  if (blockIdx.x >= 128) {  // gemm_d next layer (KD=128): 256 blocks x 128 rows
    int g = blockIdx.x - 128;
    int mloc = swz_g(g & 63) * 512 + (g >> 6) * 128 + wave * 16;
    dev_gemm128(mloc, dbf, gWT, dinv_d, htmp, 0, col, quad);
    return;
  }

  // ---------------- fused level section --------------------------------
  int b = swz_g(blockIdx.x & 63);
  int qh = blockIdx.x >> 6;
  int n0 = wave * 64;

  bf16x8 bfr[4][4];
#pragma unroll
  for (int s = 0; s < 4; ++s)
#pragma unroll
    for (int kc = 0; kc < 4; ++kc)
      bfr[s][kc] = *(const bf16x8*)(dbf + ((size_t)(b * 512 + n0 + s * 16 + col) << 7) +
                                    kc * 32 + quad * 8);
  bf16x8 aq[4];
#pragma unroll
  for (int kc = 0; kc < 4; ++kc)
    aq[kc] = *(const bf16x8*)(qbf + (size_t)(b * 32 + qh * 16 + col) * 128 +
                              kc * 32 + quad * 8);

  floatx4 att[4];
#pragma unroll
  for (int s = 0; s < 4; ++s)
#pragma unroll
    for (int r = 0; r < 4; ++r) att[s][r] = 0.0f;
#pragma unroll
  for (int kc = 0; kc < 4; ++kc)
#pragma unroll
    for (int s = 0; s < 4; ++s)
      att[s] = __builtin_amdgcn_mfma_f32_16x16x32_bf16(aq[kc], bfr[s][kc], att[s], 0, 0, 0);
  const float sc = 0.088388347648318440550f;
#pragma unroll
  for (int s = 0; s < 4; ++s)
#pragma unroll
    for (int r = 0; r < 4; ++r) att[s][r] *= sc;

  {
    bf16x8 vn2[4];
#pragma unroll
    for (int kc = 0; kc < 4; ++kc)
      vn2[kc] = *(const bf16x8*)(vnbf + col * 256 + 128 + kc * 32 + quad * 8);
#pragma unroll
    for (int s = 0; s < 4; ++s) {
      floatx4 lda;
#pragma unroll
      for (int r = 0; r < 4; ++r) lda[r] = 0.0f;
#pragma unroll
      for (int kc = 0; kc < 4; ++kc)
        lda = __builtin_amdgcn_mfma_f32_16x16x32_bf16(bfr[s][kc], vn2[kc], lda, 0, 0, 0);
#pragma unroll
      for (int r = 0; r < 4; ++r)
        s_ld[col * LD_STRIDE + n0 + s * 16 + quad * 4 + r] = lda[r];
    }
  }
  if (wave == 0) {
    bf16x8 vn1[4];
#pragma unroll
    for (int kc = 0; kc < 4; ++kc)
      vn1[kc] = *(const bf16x8*)(vnbf + col * 256 + kc * 32 + quad * 8);
    floatx4 lqa;
#pragma unroll
    for (int r = 0; r < 4; ++r) lqa[r] = 0.0f;
#pragma unroll
    for (int kc = 0; kc < 4; ++kc)
      lqa = __builtin_amdgcn_mfma_f32_16x16x32_bf16(aq[kc], vn1[kc], lqa, 0, 0, 0);
#pragma unroll
    for (int r = 0; r < 4; ++r) s_lq[col * 16 + quad * 4 + r] = lqa[r];
  }
  __syncthreads();

  float red[4], M[4];
#pragma unroll
  for (int r = 0; r < 4; ++r) {
    float m = fmaxf(fmaxf(att[0][r], att[1][r]), fmaxf(att[2][r], att[3][r]));
#pragma unroll
    for (int o = 1; o < 16; o <<= 1) m = fmaxf(m, __shfl_xor(m, o, 64));
    red[r] = m;
  }
  if (col == 0)
#pragma unroll
    for (int r = 0; r < 4; ++r) s_red[(quad * 4 + r) * 8 + wave] = red[r];
  __syncthreads();
#pragma unroll
  for (int r = 0; r < 4; ++r) {
    float m = s_red[(quad * 4 + r) * 8];
#pragma unroll
    for (int w = 1; w < 8; ++w) m = fmaxf(m, s_red[(quad * 4 + r) * 8 + w]);
    M[r] = m;
  }
  __syncthreads();
#pragma unroll
  for (int s = 0; s < 4; ++s)
#pragma unroll
    for (int r = 0; r < 4; ++r) att[s][r] = fexp(att[s][r] - M[r]);
#pragma unroll
  for (int r = 0; r < 4; ++r) {
    float m = att[0][r] + att[1][r] + att[2][r] + att[3][r];
#pragma unroll
    for (int o = 1; o < 16; o <<= 1) m += __shfl_xor(m, o, 64);
    red[r] = m;
  }
  if (col == 0)
#pragma unroll
    for (int r = 0; r < 4; ++r) s_red[(quad * 4 + r) * 8 + wave] = red[r];
  __syncthreads();
#pragma unroll
  for (int r = 0; r < 4; ++r) {
    float m = s_red[(quad * 4 + r) * 8];
#pragma unroll
    for (int w = 1; w < 8; ++w) m += s_red[(quad * 4 + r) * 8 + w];
    M[r] = frcp(m);
  }
  __syncthreads();
#pragma unroll
  for (int s = 0; s < 4; ++s)
#pragma unroll
    for (int r = 0; r < 4; ++r) att[s][r] *= M[r];

  floatx4 eacc[4], facc[4];
#pragma unroll
  for (int s = 0; s < 4; ++s)
#pragma unroll
    for (int r = 0; r < 4; ++r) { eacc[s][r] = 0.0f; facc[s][r] = 0.0f; }

#pragma unroll 4
  for (int k = 0; k < 16; ++k) {
    const ushort* qk = qw + ((size_t)(b * 16 + k) << 12) + (qh * 16 + col) * 128 + quad * 8;
    bf16x8 a0 = *(const bf16x8*)(qk);
    bf16x8 a1 = *(const bf16x8*)(qk + 32);
    bf16x8 a2 = *(const bf16x8*)(qk + 64);
    bf16x8 a3 = *(const bf16x8*)(qk + 96);
    floatx4 bil[4];
#pragma unroll
    for (int s = 0; s < 4; ++s) {
#pragma unroll
      for (int r = 0; r < 4; ++r) bil[s][r] = 0.0f;
      bil[s] = __builtin_amdgcn_mfma_f32_16x16x32_bf16(a0, bfr[s][0], bil[s], 0, 0, 0);
      bil[s] = __builtin_amdgcn_mfma_f32_16x16x32_bf16(a1, bfr[s][1], bil[s], 0, 0, 0);
      bil[s] = __builtin_amdgcn_mfma_f32_16x16x32_bf16(a2, bfr[s][2], bil[s], 0, 0, 0);
      bil[s] = __builtin_amdgcn_mfma_f32_16x16x32_bf16(a3, bfr[s][3], bil[s], 0, 0, 0);
    }
    float bnk = bn[k], cwk = cw[k];
    float wkk = 0.0f;
    if (hasF) {
      wkk = w_end[o1 + k];
      if (o2 >= 0) wkk += w_end[o2 + k];
    }
    float lqv[4];
#pragma unroll
    for (int r = 0; r < 4; ++r) lqv[r] = s_lq[k * 16 + quad * 4 + r] + bnk;
#pragma unroll
    for (int s = 0; s < 4; ++s) {
      float ldv = s_ld[k * LD_STRIDE + n0 + s * 16 + col];
#pragma unroll
      for (int r = 0; r < 4; ++r) {
        float sg = fsigmoid(bil[s][r] + lqv[r] + ldv);
        eacc[s][r] += cwk * sg;
        facc[s][r] += wkk * sg;
      }
    }
  }

#pragma unroll
  for (int s = 0; s < 4; ++s)
#pragma unroll
    for (int r = 0; r < 4; ++r) {
      eacc[s][r] *= att[s][r];
      facc[s][r] *= att[s][r];
    }
  if (do_sm) {
#pragma unroll
    for (int r = 0; r < 4; ++r) {
      float m = fmaxf(fmaxf(eacc[0][r], eacc[1][r]), fmaxf(eacc[2][r], eacc[3][r]));
#pragma unroll
      for (int o = 1; o < 16; o <<= 1) m = fmaxf(m, __shfl_xor(m, o, 64));
      red[r] = m;
    }
    if (col == 0)
#pragma unroll
      for (int r = 0; r < 4; ++r) s_red[(quad * 4 + r) * 8 + wave] = red[r];
    __syncthreads();
#pragma unroll
    for (int r = 0; r < 4; ++r) {
      float m = s_red[(quad * 4 + r) * 8];
#pragma unroll
      for (int w = 1; w < 8; ++w) m = fmaxf(m, s_red[(quad * 4 + r) * 8 + w]);
      M[r] = m;
    }
    __syncthreads();
#pragma unroll
    for (int s = 0; s < 4; ++s)
#pragma unroll
      for (int r = 0; r < 4; ++r) eacc[s][r] = fexp(eacc[s][r] - M[r]);
#pragma unroll
    for (int r = 0; r < 4; ++r) {
      float m = eacc[0][r] + eacc[1][r] + eacc[2][r] + eacc[3][r];
#pragma unroll
      for (int o = 1; o < 16; o <<= 1) m += __shfl_xor(m, o, 64);
      red[r] = m;
    }
    if (col == 0)
#pragma unroll
      for (int r = 0; r < 4; ++r) s_red[(quad * 4 + r) * 8 + wave] = red[r];
    __syncthreads();
#pragma unroll
    for (int r = 0; r < 4; ++r) {
      float m = s_red[(quad * 4 + r) * 8];
#pragma unroll
      for (int w = 1; w < 8; ++w) m += s_red[(quad * 4 + r) * 8 + w];
      M[r] = frcp(m);
    }
    __syncthreads();
#pragma unroll
    for (int s = 0; s < 4; ++s)
#pragma unroll
      for (int r = 0; r < 4; ++r) eacc[s][r] *= M[r];
  }
  float w = w_end[widx];
#pragma unroll
  for (int s = 0; s < 4; ++s)
#pragma unroll
    for (int r = 0; r < 4; ++r) eacc[s][r] = w * eacc[s][r] + (hasF ? facc[s][r] : 0.0f);

  if (mode == 0) {
#pragma unroll
    for (int s = 0; s < 4; ++s)
#pragma unroll
      for (int r = 0; r < 4; ++r)
        accb[((size_t)(b * 32 + qh * 16 + quad * 4 + r) << 9) + n0 + s * 16 + col] =
            eacc[s][r];
  } else if (mode == 1) {
#pragma unroll
    for (int s = 0; s < 4; ++s)
#pragma unroll
      for (int r = 0; r < 4; ++r)
        accb[((size_t)(b * 32 + qh * 16 + quad * 4 + r) << 9) + n0 + s * 16 + col] +=
            eacc[s][r];
  } else {
    float be = b_end[0];
#pragma unroll
    for (int s = 0; s < 4; ++s)
#pragma unroll
      for (int r = 0; r < 4; ++r)
        eacc[s][r] += accb[((size_t)(b * 32 + qh * 16 + quad * 4 + r) << 9) +
                           n0 + s * 16 + col] + be;
#pragma unroll
    for (int r = 0; r < 4; ++r) {
      float m = fmaxf(fmaxf(eacc[0][r], eacc[1][r]), fmaxf(eacc[2][r], eacc[3][r]));
#pragma unroll
      for (int o = 1; o < 16; o <<= 1) m = fmaxf(m, __shfl_xor(m, o, 64));
      red[r] = m;
    }
    if (col == 0)
#pragma unroll
      for (int r = 0; r < 4; ++r) s_red[(quad * 4 + r) * 8 + wave] = red[r];
    __syncthreads();
#pragma unroll
    for (int r = 0; r < 4; ++r) {
      float m = s_red[(quad * 4 + r) * 8];
#pragma unroll
      for (int w2 = 1; w2 < 8; ++w2) m = fmaxf(m, s_red[(quad * 4 + r) * 8 + w2]);
      M[r] = m;
    }
    __syncthreads();
#pragma unroll
    for (int s = 0; s < 4; ++s)
#pragma unroll
      for (int r = 0; r < 4; ++r) eacc[s][r] = fexp(eacc[s][r] - M[r]);
#pragma unroll
    for (int r = 0; r < 4; ++r) {
      float m = eacc[0][r] + eacc[1][r] + eacc[2][r] + eacc[3][r];
#pragma unroll
      for (int o = 1; o < 16; o <<= 1) m += __shfl_xor(m, o, 64);
      red[r] = m;
    }
    if (col == 0)
#pragma unroll
      for (int r = 0; r < 4; ++r) s_red[(quad * 4 + r) * 8 + wave] = red[r];
    __syncthreads();
#pragma unroll
    for (int r = 0; r < 4; ++r) {
      float m = s_red[(quad * 4 + r) * 8];
#pragma unroll
      for (int w2 = 1; w2 < 8; ++w2) m += s_red[(quad * 4 + r) * 8 + w2];
      M[r] = frcp(m);
    }
#pragma unroll
    for (int s = 0; s < 4; ++s)
#pragma unroll
      for (int r = 0; r < 4; ++r)
        out[((size_t)(b * 32 + qh * 16 + quad * 4 + r) << 9) + n0 + s * 16 + col] =
            eacc[s][r] * M[r];
  }
}

// ---------------------------------------------------------------------------
// Host orchestration — 11 dispatches (1 memset + 10 kernels)
// ---------------------------------------------------------------------------
extern "C" void kernel_launch(void* const* d_in, const int* in_sizes, int n_in,
                              void* d_out, int out_size, void* d_ws, size_t ws_size,
                              hipStream_t stream) {
  (void)in_sizes; (void)n_in; (void)out_size; (void)ws_size;
  const float* x_d = (const float*)d_in[0];
  const float* x_q = (const float*)d_in[1];
  const int* ei_d = (const int*)d_in[2];
  const int* ei_q = (const int*)d_in[3];
  const float* W1 = (const float*)d_in[6];
  const float* b1 = (const float*)d_in[7];
  const float* W2 = (const float*)d_in[8];
  const float* b2 = (const float*)d_in[9];
  const float* W3 = (const float*)d_in[10];
  const float* b3 = (const float*)d_in[11];
  const float* Wn[3] = {(const float*)d_in[12], (const float*)d_in[17], (const float*)d_in[22]};
  const float* Vn[3] = {(const float*)d_in[13], (const float*)d_in[18], (const float*)d_in[23]};
  const float* bn[3] = {(const float*)d_in[14], (const float*)d_in[19], (const float*)d_in[24]};
  const float* cw[3] = {(const float*)d_in[15], (const float*)d_in[20], (const float*)d_in[25]};
  const float* w_end = (const float*)d_in[27];
  const float* b_end = (const float*)d_in[28];
  float* out = (float*)d_out;

  char* wsp = (char*)d_ws;
  auto alloc = [&](size_t nbytes) {
    void* p = (void*)wsp;
    wsp += (nbytes + 255) & ~(size_t)255;
    return p;
  };
  int* cnt_d = (int*)alloc(cNd * 4);
  int* cnt_q = (int*)alloc(cNq * 4);
  int* cur_d = (int*)alloc(cNd * 4);
  int* cur_q = (int*)alloc(cNq * 4);
  float* dinv_d = (float*)alloc(cNd * 4);
  float* dinv_q = (float*)alloc(cNq * 4);
  int* rp_d = (int*)alloc(cNd * 4);
  int* rp_q = (int*)alloc(cNq * 4);
  int* col_d = (int*)alloc((size_t)cEd * 4);
  int* col_q = (int*)alloc((size_t)cEq * 4);
  ushort* xdbf = (ushort*)alloc((size_t)cNd * 64 * 2);
  ushort* xqbf = (ushort*)alloc((size_t)cNq * 64 * 2);
  ushort* w1T = (ushort*)alloc(128 * 64 * 2);
  ushort* w2T = (ushort*)alloc(128 * 128 * 2);
  ushort* w3T = (ushort*)alloc(128 * 128 * 2);
  ushort* wnT[3];
  for (int l = 0; l < 3; ++l) wnT[l] = (ushort*)alloc((size_t)16 * 128 * 128 * 2);
  ushort* vnbf[3];
  for (int l = 0; l < 3; ++l) vnbf[l] = (ushort*)alloc(16 * 256 * 2);
  ushort* htmp = (ushort*)alloc((size_t)(cNd + cNq) * 128 * 2);
  ushort* dbf = (ushort*)alloc((size_t)cNd * 128 * 2);
  ushort* qbf[3];
  for (int l = 0; l < 3; ++l) qbf[l] = (ushort*)alloc((size_t)cNq * 128 * 2);
  float* accb = (float*)alloc((size_t)cB * cNQ * cND * 4);
  ushort* qwbuf = (ushort*)alloc((size_t)cB * 16 * 32 * 128 * 2);

  const int* src_d = ei_d;
  const int* dst_d = ei_d + cEd;
  const int* src_q = ei_q;
  const int* dst_q = ei_q + cEq;

  hipMemsetAsync(cnt_d, 0, (size_t)2 * (cNd + cNq) * 4, stream);

  // D1: conversions + transposes + edge counts
  k_front<<<NB_CVT + NB_T2BF + NB_CNT, 256, 0, stream>>>(
      x_d, x_q, Vn[0], Vn[1], Vn[2], xdbf, xqbf, vnbf[0], vnbf[1], vnbf[2], W1, W2,
      W3, Wn[0], Wn[1], Wn[2], w1T, w2T, w3T, wnT[0], wnT[1], wnT[2], dst_d, dst_q,
      cnt_d, cnt_q);

  // D2: per-graph local scans + dinv
  k_scan_dinv<<<136, 512, 0, stream>>>(cnt_d, cnt_q, rp_d, rp_q, dinv_d, dinv_q);

  // D3: CSR fill + GEMM layer 1 (data + query)
  k_fill_gemm1<<<NB_FILL + 544, 256, 0, stream>>>(
      src_d, dst_d, src_q, dst_q, rp_d, rp_q, cur_d, cur_q, col_d, col_q, xdbf, xqbf,
      w1T, dinv_d, dinv_q, htmp);

  // D4: gather_d[0] + gather_q[0]
  k_e1<<<2176, 512, 0, stream>>>(0, htmp, rp_d, cnt_d, col_d, dinv_d, rp_q, cnt_q,
                                 col_q, dinv_q, b1, dbf, qbf[0], qbf[0], wnT[0],
                                 qwbuf, w2T);

  // D5: qw[0] + gemm_q[1]
  k_e1<<<528, 512, 0, stream>>>(2, htmp, rp_d, cnt_d, col_d, dinv_d, rp_q, cnt_q,
                                col_q, dinv_q, b1, dbf, qbf[0], qbf[0], wnT[0],
                                qwbuf, w2T);

  // D6: level[0] (mode 0) + gemm_d[1] + gather_q[1]
  k_e2<<<512, 512, 0, stream>>>(qbf[0], dbf, qwbuf, vnbf[0], bn[0], cw[0], w_end,
                                b_end, 0, -1, 0, 1, 0, 0, accb, out, w2T, dinv_d,
                                dinv_q, htmp, rp_q, cnt_q, col_q, b2, qbf[1]);

  // D7: gather_d[1] + qw[1] + gemm_q[2]
  k_e1<<<2576, 512, 0, stream>>>(1, htmp, rp_d, cnt_d, col_d, dinv_d, rp_q, cnt_q,
                                 col_q, dinv_q, b2, dbf, qbf[1], qbf[1], wnT[1],
                                 qwbuf, w3T);

  // D8: level[1] (raw e2, mode +=) + gemm_d[2] + gather_q[2]
  k_e2<<<512, 512, 0, stream>>>(qbf[1], dbf, qwbuf, vnbf[1], bn[1], cw[1], w_end,
                                b_end, 19, -1, 1, 0, 1, 1, accb, out, w3T, dinv_d,
                                dinv_q, htmp, rp_q, cnt_q, col_q, b3, qbf[2]);

  // D9: gather_d[2] + qw[2]  (no gemm_q)
  k_e1<<<2560, 512, 0, stream>>>(1, htmp, rp_d, cnt_d, col_d, dinv_d, rp_q, cnt_q,
                                 col_q, dinv_q, b3, dbf, qbf[2], qbf[2], wnT[2],
                                 qwbuf, w3T);

  // D10: level[2] (mode final -> out)
  k_e2<<<128, 512, 0, stream>>>(qbf[2], dbf, qwbuf, vnbf[2], bn[2], cw[2], w_end,
                                b_end, 3, 35, 1, 1, 2, 2, accb, out, w3T, dinv_d,
                                dinv_q, htmp, rp_q, cnt_q, col_q, b3, qbf[2]);
}

// Round 11
// 301.566 us; speedup vs baseline: 1.0657x; 1.0657x over previous
//
#include <hip/hip_runtime.h>
#include <math.h>

// ---------------------------------------------------------------------------
// Problem constants (fixed production sizes from the reference)
// ---------------------------------------------------------------------------
namespace {
constexpr int cB  = 64;
constexpr int cNQ = 32;
constexpr int cND = 512;
constexpr int cNd = cB * cND;   // 32768
constexpr int cNq = cB * cNQ;   // 2048
constexpr int cEd = cNd * 8;    // 262144 (exactly 4096 per graph)
constexpr int cEq = cNq * 8;    // 16384  (exactly 256 per graph)
constexpr int LD_STRIDE = 516;
constexpr int NB_CVT = 2188, NB_T2BF = 808, NB_CNT = (cEd + cEq) / 256;
constexpr int NB_FILL = (cEd + cEq) / 256;  // 1088
}

#define F4C(p) (*(const float4*)(p))

typedef __attribute__((ext_vector_type(8))) __bf16 bf16x8;
typedef __attribute__((ext_vector_type(4))) float floatx4;

__device__ __forceinline__ ushort f2bf(float f) {
  union { float f; unsigned u; } v;
  v.f = f;
  unsigned u = v.u;
  return (ushort)((u + 0x7fffu + ((u >> 16) & 1u)) >> 16);
}
__device__ __forceinline__ float bf2f(ushort u) {
  union { unsigned u; float f; } v;
  v.u = ((unsigned)u) << 16;
  return v.f;
}
__device__ __forceinline__ float4 us4f4(ushort4 u) {
  return make_float4(bf2f(u.x), bf2f(u.y), bf2f(u.z), bf2f(u.w));
}
__device__ __forceinline__ ushort4 f4us4(float4 f) {
  ushort4 o;
  o.x = f2bf(f.x); o.y = f2bf(f.y); o.z = f2bf(f.z); o.w = f2bf(f.w);
  return o;
}
__device__ __forceinline__ float fexp2(float x) {
#if __has_builtin(__builtin_amdgcn_exp2f)
  return __builtin_amdgcn_exp2f(x);
#else
  return exp2f(x);
#endif
}
__device__ __forceinline__ float frcp(float x) {
#if __has_builtin(__builtin_amdgcn_rcpf)
  return __builtin_amdgcn_rcpf(x);
#else
  return 1.0f / x;
#endif
}
__device__ __forceinline__ float fsigmoid(float z) {
  return frcp(1.0f + fexp2(z * -1.4426950408889634f));
}
__device__ __forceinline__ float fexp(float x) { return fexp2(x * 1.4426950408889634f); }

// Temporal-locality XCD swizzle for a section of 64*S blocks (S = 2^L subs per
// graph): XCD = blk%8 (round-robin heuristic); within one XCD the sub-index
// changes fastest and the graph slowest -> 1-2 graphs live per L2 at a time.
//   g   = ((blk >> (3+L)) << 3) | (blk & 7)
//   sub = (blk >> 3) & (S-1)
template <int L>
__device__ __forceinline__ int swzg(int j) { return ((j >> (3 + L)) << 3) | (j & 7); }
template <int L>
__device__ __forceinline__ int swzs(int j) { return (j >> 3) & ((1 << L) - 1); }

// ---------------------------------------------------------------------------
// D1 front: conversions + weight transposes + edge counts. grid 4084 x 256.
// ---------------------------------------------------------------------------
__global__ __launch_bounds__(256) void k_front(
    const float* __restrict__ xd, const float* __restrict__ xq,
    const float* __restrict__ v0, const float* __restrict__ v1,
    const float* __restrict__ v2, ushort* __restrict__ oxd, ushort* __restrict__ oxq,
    ushort* __restrict__ ov0, ushort* __restrict__ ov1, ushort* __restrict__ ov2,
    const float* __restrict__ W1, const float* __restrict__ W2,
    const float* __restrict__ W3, const float* __restrict__ Wn0,
    const float* __restrict__ Wn1, const float* __restrict__ Wn2,
    ushort* __restrict__ o1, ushort* __restrict__ o2, ushort* __restrict__ o3,
    ushort* __restrict__ on0, ushort* __restrict__ on1, ushort* __restrict__ on2,
    const int* __restrict__ dst_d, const int* __restrict__ dst_q,
    int* __restrict__ cnt_d, int* __restrict__ cnt_q) {
  __shared__ float tile[32][33];
  int blk = blockIdx.x, tid = threadIdx.x;
  if (blk < NB_CVT) {
    const float* src;
    ushort* dst;
    int i;
    if (blk < 2048) { src = xd; dst = oxd; i = blk * 256 + tid; }
    else if (blk < 2176) { src = xq; dst = oxq; i = (blk - 2048) * 256 + tid; }
    else if (blk < 2180) { src = v0; dst = ov0; i = (blk - 2176) * 256 + tid; }
    else if (blk < 2184) { src = v1; dst = ov1; i = (blk - 2180) * 256 + tid; }
    else { src = v2; dst = ov2; i = (blk - 2184) * 256 + tid; }
    *(ushort4*)(dst + (size_t)i * 4) = f4us4(F4C(src + (size_t)i * 4));
  } else if (blk < NB_CVT + NB_T2BF) {
    int b5 = blk - NB_CVT;
    const float* in;
    ushort* out;
    int R, C, bt, t;
    if (b5 < 8)        { in = W1;  out = o1;  R = 64;  C = 128; bt = 0; t = b5; }
    else if (b5 < 24)  { in = W2;  out = o2;  R = 128; C = 128; bt = 0; t = b5 - 8; }
    else if (b5 < 40)  { in = W3;  out = o3;  R = 128; C = 128; bt = 0; t = b5 - 24; }
    else if (b5 < 296) { in = Wn0; out = on0; R = 128; C = 128; bt = (b5 - 40) >> 4;  t = (b5 - 40) & 15; }
    else if (b5 < 552) { in = Wn1; out = on1; R = 128; C = 128; bt = (b5 - 296) >> 4; t = (b5 - 296) & 15; }
    else               { in = Wn2; out = on2; R = 128; C = 128; bt = (b5 - 552) >> 4; t = (b5 - 552) & 15; }
    int tilesC = C >> 5;
    int tr = t / tilesC, tc = t - tr * tilesC;
    int tx = tid & 31, ty = tid >> 5;
    const float* ib = in + (size_t)bt * R * C;
    ushort* ob = out + (size_t)bt * R * C;
#pragma unroll
    for (int i = 0; i < 4; ++i)
      tile[ty + i * 8][tx] = ib[(tr * 32 + ty + i * 8) * C + tc * 32 + tx];
    __syncthreads();
#pragma unroll
    for (int i = 0; i < 4; ++i)
      ob[(size_t)(tc * 32 + ty + i * 8) * R + tr * 32 + tx] = f2bf(tile[tx][ty + i * 8]);
  } else {
    int i = (blk - NB_CVT - NB_T2BF) * 256 + tid;
    if (i < cEd) atomicAdd(&cnt_d[dst_d[i]], 1);
    else atomicAdd(&cnt_q[dst_q[i - cEd]], 1);
  }
}

// ---------------------------------------------------------------------------
// D2: per-graph local scans + dinv. grid 136 x 512.
// ---------------------------------------------------------------------------
__global__ __launch_bounds__(512) void k_scan_dinv(
    const int* __restrict__ cnt_d, const int* __restrict__ cnt_q,
    int* __restrict__ rp_d, int* __restrict__ rp_q,
    float* __restrict__ dinv_d, float* __restrict__ dinv_q) {
  __shared__ int sh[512];
  int blk = blockIdx.x, tid = threadIdx.x;
  if (blk < 64) {
    int v = cnt_d[blk * 512 + tid];
    sh[tid] = v;
    __syncthreads();
    for (int off = 1; off < 512; off <<= 1) {
      int t = (tid >= off) ? sh[tid - off] : 0;
      __syncthreads();
      sh[tid] += t;
      __syncthreads();
    }
    rp_d[blk * 512 + tid] = blk * 4096 + sh[tid] - v;
  } else if (blk < 68) {
    int g = (blk - 64) * 16 + (tid >> 5);
    int lane32 = tid & 31;
    int v = cnt_q[g * 32 + lane32];
    int incl = v;
#pragma unroll
    for (int off = 1; off < 32; off <<= 1) {
      int t = __shfl_up(incl, off, 32);
      if (lane32 >= off) incl += t;
    }
    rp_q[g * 32 + lane32] = g * 256 + incl - v;
  } else {
    int i = (blk - 68) * 512 + tid;
    if (i < cNd) dinv_d[i] = 1.0f / sqrtf((float)(cnt_d[i] + 1));
    else dinv_q[i - cNd] = 1.0f / sqrtf((float)(cnt_q[i - cNd] + 1));
  }
}

// ---------------------------------------------------------------------------
// D3: CSR fill + full GCN GEMM layer 1 (KD=64). grid 1632 x 256.
// ---------------------------------------------------------------------------
__global__ __launch_bounds__(256) void k_fill_gemm1(
    const int* __restrict__ src_d, const int* __restrict__ dst_d,
    const int* __restrict__ src_q, const int* __restrict__ dst_q,
    const int* __restrict__ rp_d, const int* __restrict__ rp_q,
    int* __restrict__ cur_d, int* __restrict__ cur_q, int* __restrict__ col_d,
    int* __restrict__ col_q, const ushort* __restrict__ xdbf,
    const ushort* __restrict__ xqbf, const ushort* __restrict__ w1T,
    const float* __restrict__ dinv_d, const float* __restrict__ dinv_q,
    ushort* __restrict__ htmp) {
  int blk = blockIdx.x, tid = threadIdx.x;
  if (blk < NB_FILL) {
    int i = blk * 256 + tid;
    if (i < cEd) {
      int d = dst_d[i];
      int p = atomicAdd(&cur_d[d], 1);
      col_d[rp_d[d] + p] = src_d[i];
    } else {
      int j = i - cEd;
      int d = dst_q[j];
      int p = atomicAdd(&cur_q[d], 1);
      col_q[rp_q[d] + p] = src_q[j];
    }
    return;
  }
  int blk2 = blk - NB_FILL;  // [0,544): data [0,512) swizzled S=8, query rest
  int wave = tid >> 6, lane = tid & 63;
  int col = lane & 15, quad = lane >> 4;
  bool isQ = blk2 >= 512;
  int node0;
  if (isQ) node0 = (blk2 - 512) * 64;
  else node0 = swzg<3>(blk2) * 512 + swzs<3>(blk2) * 64;
  int mloc = node0 + wave * 16;
  const ushort* X = isQ ? xqbf : xdbf;
  const float* dv = isQ ? dinv_q : dinv_d;
  size_t hbase = isQ ? (size_t)cNd : 0;
  floatx4 acc[8];
#pragma unroll
  for (int ct = 0; ct < 8; ++ct)
#pragma unroll
    for (int r = 0; r < 4; ++r) acc[ct][r] = 0.0f;
#pragma unroll
  for (int kc = 0; kc < 2; ++kc) {
    bf16x8 a = *(const bf16x8*)(X + (size_t)(mloc + col) * 64 + kc * 32 + quad * 8);
#pragma unroll
    for (int ct = 0; ct < 8; ++ct) {
      bf16x8 b = *(const bf16x8*)(w1T + (size_t)(ct * 16 + col) * 64 + kc * 32 + quad * 8);
      acc[ct] = __builtin_amdgcn_mfma_f32_16x16x32_bf16(a, b, acc[ct], 0, 0, 0);
    }
  }
  float sc[4];
#pragma unroll
  for (int r = 0; r < 4; ++r) sc[r] = dv[mloc + quad * 4 + r];
#pragma unroll
  for (int ct = 0; ct < 8; ++ct)
#pragma unroll
    for (int r = 0; r < 4; ++r)
      htmp[(hbase + mloc + quad * 4 + r) * 128 + ct * 16 + col] = f2bf(acc[ct][r] * sc[r]);
}

// ---------------------------------------------------------------------------
// GCN aggregate (temporal XCD swizzle, predicated loads). grid 4352 x 256.
// data [0,4096) S=64; query [4096,4352) S=4. 8 nodes/block, 32 lanes/node.
// ---------------------------------------------------------------------------
__global__ __launch_bounds__(256) void gmn_gather_merged(
    const ushort* __restrict__ htmp, const int* __restrict__ rp_d,
    const int* __restrict__ cnt_d, const int* __restrict__ col_d,
    const float* __restrict__ dinv_d, const int* __restrict__ rp_q,
    const int* __restrict__ cnt_q, const int* __restrict__ col_q,
    const float* __restrict__ dinv_q, const float* __restrict__ bias,
    ushort* __restrict__ dbf, ushort* __restrict__ qbf) {
  int blk = blockIdx.x, tid = threadIdx.x;
  bool isQ = blk >= 4096;
  int node;
  if (isQ) {
    int j = blk - 4096;
    node = swzg<2>(j) * 32 + swzs<2>(j) * 8 + (tid >> 5);
  } else {
    node = swzg<6>(blk) * 512 + swzs<6>(blk) * 8 + (tid >> 5);
  }
  int l = tid & 31;
  const ushort* hs = htmp + (isQ ? (size_t)cNd * 128 : 0);
  const int* rp = isQ ? rp_q : rp_d;
  const int* cnt = isQ ? cnt_q : cnt_d;
  const int* col = isQ ? col_q : col_d;
  const float* dinv = isQ ? dinv_q : dinv_d;
  ushort* outp = isQ ? qbf : dbf;
  int c = cnt[node], s0 = rp[node];
  float dt = dinv[node];
  float4 acc = us4f4(*(const ushort4*)(hs + (size_t)node * 128 + l * 4));
  int cm = c < 32 ? c : 32;
  for (int j0 = 0; j0 < cm; j0 += 8) {
    int ss[8];
    ushort4 v[8];
#pragma unroll
    for (int t = 0; t < 8; ++t) {
      int jj = j0 + t;
      ss[t] = (jj < cm) ? col[s0 + jj] : -1;
    }
#pragma unroll
    for (int t = 0; t < 8; ++t)
      if (ss[t] >= 0) v[t] = *(const ushort4*)(hs + (size_t)ss[t] * 128 + l * 4);
#pragma unroll
    for (int t = 0; t < 8; ++t) {
      if (ss[t] >= 0) {
        float4 f = us4f4(v[t]);
        acc.x += f.x; acc.y += f.y; acc.z += f.z; acc.w += f.w;
      }
    }
  }
  for (int j = 32; j < c; ++j) {
    int s = col[s0 + j];
    float4 f = us4f4(*(const ushort4*)(hs + (size_t)s * 128 + l * 4));
    acc.x += f.x; acc.y += f.y; acc.z += f.z; acc.w += f.w;
  }
  float4 bv = F4C(bias + l * 4);
  float4 r;
  r.x = fmaxf(acc.x * dt + bv.x, 0.0f);
  r.y = fmaxf(acc.y * dt + bv.y, 0.0f);
  r.z = fmaxf(acc.z * dt + bv.z, 0.0f);
  r.w = fmaxf(acc.w * dt + bv.w, 0.0f);
  *(ushort4*)(outp + (size_t)node * 128 + l * 4) = f4us4(r);
}

// ---------------------------------------------------------------------------
// qW prep (temporal XCD swizzle, S=16): qW[b,k] = q[b] @ Wn[k]. grid 1024.
// ---------------------------------------------------------------------------
__global__ __launch_bounds__(256) void gmn_qw(const ushort* __restrict__ qbf,
                                              const ushort* __restrict__ wnT,
                                              ushort* __restrict__ qw) {
  int blk = blockIdx.x, tid = threadIdx.x;
  int wave = tid >> 6, lane = tid & 63;
  int col = lane & 15, quad = lane >> 4;
  int b = swzg<4>(blk), k = swzs<4>(blk);
  int et0 = wave * 2;
  floatx4 acc[2][2];
#pragma unroll
  for (int qt = 0; qt < 2; ++qt)
#pragma unroll
    for (int ei = 0; ei < 2; ++ei)
#pragma unroll
      for (int r = 0; r < 4; ++r) acc[qt][ei][r] = 0.0f;
#pragma unroll
  for (int kc = 0; kc < 4; ++kc) {
    bf16x8 a0 = *(const bf16x8*)(qbf + (size_t)(b * 32 + col) * 128 + kc * 32 + quad * 8);
    bf16x8 a1 = *(const bf16x8*)(qbf + (size_t)(b * 32 + 16 + col) * 128 + kc * 32 + quad * 8);
#pragma unroll
    for (int ei = 0; ei < 2; ++ei) {
      bf16x8 bf = *(const bf16x8*)(wnT + (size_t)(k * 128 + (et0 + ei) * 16 + col) * 128 +
                                   kc * 32 + quad * 8);
      acc[0][ei] = __builtin_amdgcn_mfma_f32_16x16x32_bf16(a0, bf, acc[0][ei], 0, 0, 0);
      acc[1][ei] = __builtin_amdgcn_mfma_f32_16x16x32_bf16(a1, bf, acc[1][ei], 0, 0, 0);
    }
  }
#pragma unroll
  for (int qt = 0; qt < 2; ++qt)
#pragma unroll
    for (int ei = 0; ei < 2; ++ei)
#pragma unroll
      for (int r = 0; r < 4; ++r)
        qw[((size_t)(b * 16 + k) << 12) + (qt * 16 + quad * 4 + r) * 128 +
           (et0 + ei) * 16 + col] = f2bf(acc[qt][ei][r]);
}

// ---------------------------------------------------------------------------
// Merged dispatch: row-complete fused NTN level [blk<128, S=2] +
// next-layer GCN GEMM KD=128 [blk in [128,128+nb), data S=4].
// ---------------------------------------------------------------------------
__global__ __launch_bounds__(512, 2) void k_level_gemm(
    const ushort* __restrict__ qbf, const ushort* __restrict__ dbf,
    const ushort* __restrict__ qw, const ushort* __restrict__ vnbf,
    const float* __restrict__ bn, const float* __restrict__ cw,
    const float* __restrict__ w_end, const float* __restrict__ b_end,
    int o1, int o2, int hasF, int do_sm, int mode, int widx,
    float* __restrict__ accb, float* __restrict__ out,
    const ushort* __restrict__ gWT, const float* __restrict__ dinv_d,
    const float* __restrict__ dinv_q, ushort* __restrict__ htmp) {
  __shared__ float s_ld[16 * LD_STRIDE];
  __shared__ float s_lq[16 * 16];
  __shared__ float s_red[16 * 8];
  int tid = threadIdx.x;
  int wave = tid >> 6, lane = tid & 63;
  int col = lane & 15, quad = lane >> 4;

  if (blockIdx.x >= 128) {  // GEMM KD=128: data [0,256) S=4, query [256,272)
    int gblk = blockIdx.x - 128;
    bool isQ = gblk >= 256;
    int node0;
    if (isQ) node0 = (gblk - 256) * 128;
    else node0 = swzg<2>(gblk) * 512 + swzs<2>(gblk) * 128;
    int mloc = node0 + wave * 16;
    const ushort* X = isQ ? qbf : dbf;
    const float* dv = isQ ? dinv_q : dinv_d;
    size_t hbase = isQ ? (size_t)cNd : 0;
    floatx4 acc[8];
#pragma unroll
    for (int ct = 0; ct < 8; ++ct)
#pragma unroll
      for (int r = 0; r < 4; ++r) acc[ct][r] = 0.0f;
#pragma unroll
    for (int kc = 0; kc < 4; ++kc) {
      bf16x8 a = *(const bf16x8*)(X + (size_t)(mloc + col) * 128 + kc * 32 + quad * 8);
#pragma unroll
      for (int ct = 0; ct < 8; ++ct) {
        bf16x8 b = *(const bf16x8*)(gWT + (size_t)(ct * 16 + col) * 128 + kc * 32 + quad * 8);
        acc[ct] = __builtin_amdgcn_mfma_f32_16x16x32_bf16(a, b, acc[ct], 0, 0, 0);
      }
    }
    float sc[4];
#pragma unroll
    for (int r = 0; r < 4; ++r) sc[r] = dv[mloc + quad * 4 + r];
#pragma unroll
    for (int ct = 0; ct < 8; ++ct)
#pragma unroll
      for (int r = 0; r < 4; ++r)
        htmp[(hbase + mloc + quad * 4 + r) * 128 + ct * 16 + col] = f2bf(acc[ct][r] * sc[r]);
    return;
  }

  // ---------------- fused level section ------------------------------------
  int b = swzg<1>(blockIdx.x);
  int qh = swzs<1>(blockIdx.x);
  int n0 = wave * 64;

  bf16x8 bfr[4][4];
#pragma unroll
  for (int s = 0; s < 4; ++s)
#pragma unroll
    for (int kc = 0; kc < 4; ++kc)
      bfr[s][kc] = *(const bf16x8*)(dbf + ((size_t)(b * 512 + n0 + s * 16 + col) << 7) +
                                    kc * 32 + quad * 8);
  bf16x8 aq[4];
#pragma unroll
  for (int kc = 0; kc < 4; ++kc)
    aq[kc] = *(const bf16x8*)(qbf + (size_t)(b * 32 + qh * 16 + col) * 128 +
                              kc * 32 + quad * 8);

  floatx4 att[4];
#pragma unroll
  for (int s = 0; s < 4; ++s)
#pragma unroll
    for (int r = 0; r < 4; ++r) att[s][r] = 0.0f;
#pragma unroll
  for (int kc = 0; kc < 4; ++kc)
#pragma unroll
    for (int s = 0; s < 4; ++s)
      att[s] = __builtin_amdgcn_mfma_f32_16x16x32_bf16(aq[kc], bfr[s][kc], att[s], 0, 0, 0);
  const float sc = 0.088388347648318440550f;
#pragma unroll
  for (int s = 0; s < 4; ++s)
#pragma unroll
    for (int r = 0; r < 4; ++r) att[s][r] *= sc;

  {
    bf16x8 vn2[4];
#pragma unroll
    for (int kc = 0; kc < 4; ++kc)
      vn2[kc] = *(const bf16x8*)(vnbf + col * 256 + 128 + kc * 32 + quad * 8);
#pragma unroll
    for (int s = 0; s < 4; ++s) {
      floatx4 lda;
#pragma unroll
      for (int r = 0; r < 4; ++r) lda[r] = 0.0f;
#pragma unroll
      for (int kc = 0; kc < 4; ++kc)
        lda = __builtin_amdgcn_mfma_f32_16x16x32_bf16(bfr[s][kc], vn2[kc], lda, 0, 0, 0);
#pragma unroll
      for (int r = 0; r < 4; ++r)
        s_ld[col * LD_STRIDE + n0 + s * 16 + quad * 4 + r] = lda[r];
    }
  }
  if (wave == 0) {
    bf16x8 vn1[4];
#pragma unroll
    for (int kc = 0; kc < 4; ++kc)
      vn1[kc] = *(const bf16x8*)(vnbf + col * 256 + kc * 32 + quad * 8);
    floatx4 lqa;
#pragma unroll
    for (int r = 0; r < 4; ++r) lqa[r] = 0.0f;
#pragma unroll
    for (int kc = 0; kc < 4; ++kc)
      lqa = __builtin_amdgcn_mfma_f32_16x16x32_bf16(aq[kc], vn1[kc], lqa, 0, 0, 0);
#pragma unroll
    for (int r = 0; r < 4; ++r) s_lq[col * 16 + quad * 4 + r] = lqa[r];
  }
  __syncthreads();

  float red[4], M[4];
#pragma unroll
  for (int r = 0; r < 4; ++r) {
    float m = fmaxf(fmaxf(att[0][r], att[1][r]), fmaxf(att[2][r], att[3][r]));
#pragma unroll
    for (int o = 1; o < 16; o <<= 1) m = fmaxf(m, __shfl_xor(m, o, 64));
    red[r] = m;
  }
  if (col == 0)
#pragma unroll
    for (int r = 0; r < 4; ++r) s_red[(quad * 4 + r) * 8 + wave] = red[r];
  __syncthreads();
#pragma unroll
  for (int r = 0; r < 4; ++r) {
    float m = s_red[(quad * 4 + r) * 8];
#pragma unroll
    for (int w = 1; w < 8; ++w) m = fmaxf(m, s_red[(quad * 4 + r) * 8 + w]);
    M[r] = m;
  }
  __syncthreads();
#pragma unroll
  for (int s = 0; s < 4; ++s)
#pragma unroll
    for (int r = 0; r < 4; ++r) att[s][r] = fexp(att[s][r] - M[r]);
#pragma unroll
  for (int r = 0; r < 4; ++r) {
    float m = att[0][r] + att[1][r] + att[2][r] + att[3][r];
#pragma unroll
    for (int o = 1; o < 16; o <<= 1) m += __shfl_xor(m, o, 64);
    red[r] = m;
  }
  if (col == 0)
#pragma unroll
    for (int r = 0; r < 4; ++r) s_red[(quad * 4 + r) * 8 + wave] = red[r];
  __syncthreads();
#pragma unroll
  for (int r = 0; r < 4; ++r) {
    float m = s_red[(quad * 4 + r) * 8];
#pragma unroll
    for (int w = 1; w < 8; ++w) m += s_red[(quad * 4 + r) * 8 + w];
    M[r] = frcp(m);
  }
  __syncthreads();
#pragma unroll
  for (int s = 0; s < 4; ++s)
#pragma unroll
    for (int r = 0; r < 4; ++r) att[s][r] *= M[r];

  floatx4 eacc[4], facc[4];
#pragma unroll
  for (int s = 0; s < 4; ++s)
#pragma unroll
    for (int r = 0; r < 4; ++r) { eacc[s][r] = 0.0f; facc[s][r] = 0.0f; }

#pragma unroll 4
  for (int k = 0; k < 16; ++k) {
    const ushort* qk = qw + ((size_t)(b * 16 + k) << 12) + (qh * 16 + col) * 128 + quad * 8;
    bf16x8 a0 = *(const bf16x8*)(qk);
    bf16x8 a1 = *(const bf16x8*)(qk + 32);
    bf16x8 a2 = *(const bf16x8*)(qk + 64);
    bf16x8 a3 = *(const bf16x8*)(qk + 96);
    floatx4 bil[4];
#pragma unroll
    for (int s = 0; s < 4; ++s) {
#pragma unroll
      for (int r = 0; r < 4; ++r) bil[s][r] = 0.0f;
      bil[s] = __builtin_amdgcn_mfma_f32_16x16x32_bf16(a0, bfr[s][0], bil[s], 0, 0, 0);
      bil[s] = __builtin_amdgcn_mfma_f32_16x16x32_bf16(a1, bfr[s][1], bil[s], 0, 0, 0);
      bil[s] = __builtin_amdgcn_mfma_f32_16x16x32_bf16(a2, bfr[s][2], bil[s], 0, 0, 0);
      bil[s] = __builtin_amdgcn_mfma_f32_16x16x32_bf16(a3, bfr[s][3], bil[s], 0, 0, 0);
    }
    float bnk = bn[k], cwk = cw[k];
    float wkk = 0.0f;
    if (hasF) {
      wkk = w_end[o1 + k];
      if (o2 >= 0) wkk += w_end[o2 + k];
    }
    float lqv[4];
#pragma unroll
    for (int r = 0; r < 4; ++r) lqv[r] = s_lq[k * 16 + quad * 4 + r] + bnk;
#pragma unroll
    for (int s = 0; s < 4; ++s) {
      float ldv = s_ld[k * LD_STRIDE + n0 + s * 16 + col];
#pragma unroll
      for (int r = 0; r < 4; ++r) {
        float sg = fsigmoid(bil[s][r] + lqv[r] + ldv);
        eacc[s][r] += cwk * sg;
        facc[s][r] += wkk * sg;
      }
    }
  }

#pragma unroll
  for (int s = 0; s < 4; ++s)
#pragma unroll
    for (int r = 0; r < 4; ++r) {
      eacc[s][r] *= att[s][r];
      facc[s][r] *= att[s][r];
    }
  if (do_sm) {
#pragma unroll
    for (int r = 0; r < 4; ++r) {
      float m = fmaxf(fmaxf(eacc[0][r], eacc[1][r]), fmaxf(eacc[2][r], eacc[3][r]));
#pragma unroll
      for (int o = 1; o < 16; o <<= 1) m = fmaxf(m, __shfl_xor(m, o, 64));
      red[r] = m;
    }
    if (col == 0)
#pragma unroll
      for (int r = 0; r < 4; ++r) s_red[(quad * 4 + r) * 8 + wave] = red[r];
    __syncthreads();
#pragma unroll
    for (int r = 0; r < 4; ++r) {
      float m = s_red[(quad * 4 + r) * 8];
#pragma unroll
      for (int w = 1; w < 8; ++w) m = fmaxf(m, s_red[(quad * 4 + r) * 8 + w]);
      M[r] = m;
    }
    __syncthreads();
#pragma unroll
    for (int s = 0; s < 4; ++s)
#pragma unroll
      for (int r = 0; r < 4; ++r) eacc[s][r] = fexp(eacc[s][r] - M[r]);
#pragma unroll
    for (int r = 0; r < 4; ++r) {
      float m = eacc[0][r] + eacc[1][r] + eacc[2][r] + eacc[3][r];
#pragma unroll
      for (int o = 1; o < 16; o <<= 1) m += __shfl_xor(m, o, 64);
      red[r] = m;
    }
    if (col == 0)
#pragma unroll
      for (int r = 0; r < 4; ++r) s_red[(quad * 4 + r) * 8 + wave] = red[r];
    __syncthreads();
#pragma unroll
    for (int r = 0; r < 4; ++r) {
      float m = s_red[(quad * 4 + r) * 8];
#pragma unroll
      for (int w = 1; w < 8; ++w) m += s_red[(quad * 4 + r) * 8 + w];
      M[r] = frcp(m);
    }
    __syncthreads();
#pragma unroll
    for (int s = 0; s < 4; ++s)
#pragma unroll
      for (int r = 0; r < 4; ++r) eacc[s][r] *= M[r];
  }
  float w = w_end[widx];
#pragma unroll
  for (int s = 0; s < 4; ++s)
#pragma unroll
    for (int r = 0; r < 4; ++r) eacc[s][r] = w * eacc[s][r] + (hasF ? facc[s][r] : 0.0f);

  if (mode == 0) {
#pragma unroll
    for (int s = 0; s < 4; ++s)
#pragma unroll
      for (int r = 0; r < 4; ++r)
        accb[((size_t)(b * 32 + qh * 16 + quad * 4 + r) << 9) + n0 + s * 16 + col] =
            eacc[s][r];
  } else if (mode == 1) {
#pragma unroll
    for (int s = 0; s < 4; ++s)
#pragma unroll
      for (int r = 0; r < 4; ++r)
        accb[((size_t)(b * 32 + qh * 16 + quad * 4 + r) << 9) + n0 + s * 16 + col] +=
            eacc[s][r];
  } else {
    float be = b_end[0];
#pragma unroll
    for (int s = 0; s < 4; ++s)
#pragma unroll
      for (int r = 0; r < 4; ++r)
        eacc[s][r] += accb[((size_t)(b * 32 + qh * 16 + quad * 4 + r) << 9) +
                           n0 + s * 16 + col] + be;
#pragma unroll
    for (int r = 0; r < 4; ++r) {
      float m = fmaxf(fmaxf(eacc[0][r], eacc[1][r]), fmaxf(eacc[2][r], eacc[3][r]));
#pragma unroll
      for (int o = 1; o < 16; o <<= 1) m = fmaxf(m, __shfl_xor(m, o, 64));
      red[r] = m;
    }
    if (col == 0)
#pragma unroll
      for (int r = 0; r < 4; ++r) s_red[(quad * 4 + r) * 8 + wave] = red[r];
    __syncthreads();
#pragma unroll
    for (int r = 0; r < 4; ++r) {
      float m = s_red[(quad * 4 + r) * 8];
#pragma unroll
      for (int w2 = 1; w2 < 8; ++w2) m = fmaxf(m, s_red[(quad * 4 + r) * 8 + w2]);
      M[r] = m;
    }
    __syncthreads();
#pragma unroll
    for (int s = 0; s < 4; ++s)
#pragma unroll
      for (int r = 0; r < 4; ++r) eacc[s][r] = fexp(eacc[s][r] - M[r]);
#pragma unroll
    for (int r = 0; r < 4; ++r) {
      float m = eacc[0][r] + eacc[1][r] + eacc[2][r] + eacc[3][r];
#pragma unroll
      for (int o = 1; o < 16; o <<= 1) m += __shfl_xor(m, o, 64);
      red[r] = m;
    }
    if (col == 0)
#pragma unroll
      for (int r = 0; r < 4; ++r) s_red[(quad * 4 + r) * 8 + wave] = red[r];
    __syncthreads();
#pragma unroll
    for (int r = 0; r < 4; ++r) {
      float m = s_red[(quad * 4 + r) * 8];
#pragma unroll
      for (int w2 = 1; w2 < 8; ++w2) m += s_red[(quad * 4 + r) * 8 + w2];
      M[r] = frcp(m);
    }
#pragma unroll
    for (int s = 0; s < 4; ++s)
#pragma unroll
      for (int r = 0; r < 4; ++r)
        out[((size_t)(b * 32 + qh * 16 + quad * 4 + r) << 9) + n0 + s * 16 + col] =
            eacc[s][r] * M[r];
  }
}

// ---------------------------------------------------------------------------
// Host orchestration — 13 dispatches (1 memset + 12 kernels), R9 structure
// ---------------------------------------------------------------------------
extern "C" void kernel_launch(void* const* d_in, const int* in_sizes, int n_in,
                              void* d_out, int out_size, void* d_ws, size_t ws_size,
                              hipStream_t stream) {
  (void)in_sizes; (void)n_in; (void)out_size; (void)ws_size;
  const float* x_d = (const float*)d_in[0];
  const float* x_q = (const float*)d_in[1];
  const int* ei_d = (const int*)d_in[2];
  const int* ei_q = (const int*)d_in[3];
  const float* W1 = (const float*)d_in[6];
  const float* b1 = (const float*)d_in[7];
  const float* W2 = (const float*)d_in[8];
  const float* b2 = (const float*)d_in[9];
  const float* W3 = (const float*)d_in[10];
  const float* b3 = (const float*)d_in[11];
  const float* Wn[3] = {(const float*)d_in[12], (const float*)d_in[17], (const float*)d_in[22]};
  const float* Vn[3] = {(const float*)d_in[13], (const float*)d_in[18], (const float*)d_in[23]};
  const float* bn[3] = {(const float*)d_in[14], (const float*)d_in[19], (const float*)d_in[24]};
  const float* cw[3] = {(const float*)d_in[15], (const float*)d_in[20], (const float*)d_in[25]};
  const float* w_end = (const float*)d_in[27];
  const float* b_end = (const float*)d_in[28];
  float* out = (float*)d_out;

  char* wsp = (char*)d_ws;
  auto alloc = [&](size_t nbytes) {
    void* p = (void*)wsp;
    wsp += (nbytes + 255) & ~(size_t)255;
    return p;
  };
  int* cnt_d = (int*)alloc(cNd * 4);
  int* cnt_q = (int*)alloc(cNq * 4);
  int* cur_d = (int*)alloc(cNd * 4);
  int* cur_q = (int*)alloc(cNq * 4);
  float* dinv_d = (float*)alloc(cNd * 4);
  float* dinv_q = (float*)alloc(cNq * 4);
  int* rp_d = (int*)alloc(cNd * 4);
  int* rp_q = (int*)alloc(cNq * 4);
  int* col_d = (int*)alloc((size_t)cEd * 4);
  int* col_q = (int*)alloc((size_t)cEq * 4);
  ushort* xdbf = (ushort*)alloc((size_t)cNd * 64 * 2);
  ushort* xqbf = (ushort*)alloc((size_t)cNq * 64 * 2);
  ushort* w1T = (ushort*)alloc(128 * 64 * 2);
  ushort* w2T = (ushort*)alloc(128 * 128 * 2);
  ushort* w3T = (ushort*)alloc(128 * 128 * 2);
  ushort* wnT[3];
  for (int l = 0; l < 3; ++l) wnT[l] = (ushort*)alloc((size_t)16 * 128 * 128 * 2);
  ushort* vnbf[3];
  for (int l = 0; l < 3; ++l) vnbf[l] = (ushort*)alloc(16 * 256 * 2);
  ushort* htmp = (ushort*)alloc((size_t)(cNd + cNq) * 128 * 2);
  ushort* dbf = (ushort*)alloc((size_t)cNd * 128 * 2);
  ushort* qbf[3];
  for (int l = 0; l < 3; ++l) qbf[l] = (ushort*)alloc((size_t)cNq * 128 * 2);
  float* accb = (float*)alloc((size_t)cB * cNQ * cND * 4);
  ushort* qwbuf = (ushort*)alloc((size_t)cB * 16 * 32 * 128 * 2);

  const int* src_d = ei_d;
  const int* dst_d = ei_d + cEd;
  const int* src_q = ei_q;
  const int* dst_q = ei_q + cEq;

  hipMemsetAsync(cnt_d, 0, (size_t)2 * (cNd + cNq) * 4, stream);

  // D1: conversions + transposes + edge counts
  k_front<<<NB_CVT + NB_T2BF + NB_CNT, 256, 0, stream>>>(
      x_d, x_q, Vn[0], Vn[1], Vn[2], xdbf, xqbf, vnbf[0], vnbf[1], vnbf[2], W1, W2,
      W3, Wn[0], Wn[1], Wn[2], w1T, w2T, w3T, wnT[0], wnT[1], wnT[2], dst_d, dst_q,
      cnt_d, cnt_q);

  // D2: per-graph local scans + dinv
  k_scan_dinv<<<136, 512, 0, stream>>>(cnt_d, cnt_q, rp_d, rp_q, dinv_d, dinv_q);

  // D3: CSR fill + GEMM layer 1 (data + query)
  k_fill_gemm1<<<NB_FILL + 544, 256, 0, stream>>>(
      src_d, dst_d, src_q, dst_q, rp_d, rp_q, cur_d, cur_q, col_d, col_q, xdbf, xqbf,
      w1T, dinv_d, dinv_q, htmp);

  const float* bias[3] = {b1, b2, b3};
  const ushort* nextWT[3] = {w2T, w3T, nullptr};
  const int o1s[3] = {0, 19, 3};
  const int o2s[3] = {-1, -1, 35};
  const int hasF[3] = {0, 1, 1};
  const int dosms[3] = {1, 0, 1};
  const int modes[3] = {0, 1, 2};

  for (int l = 0; l < 3; ++l) {
    gmn_gather_merged<<<(cNd + cNq) / 8, 256, 0, stream>>>(
        htmp, rp_d, cnt_d, col_d, dinv_d, rp_q, cnt_q, col_q, dinv_q, bias[l], dbf,
        qbf[l]);
    gmn_qw<<<1024, 256, 0, stream>>>(qbf[l], wnT[l], qwbuf);
    int grid = (l < 2) ? (128 + 272) : 128;
    k_level_gemm<<<grid, 512, 0, stream>>>(
        qbf[l], dbf, qwbuf, vnbf[l], bn[l], cw[l], w_end, b_end, o1s[l], o2s[l],
        hasF[l], dosms[l], modes[l], l, accb, out, nextWT[l], dinv_d, dinv_q, htmp);
  }
}